// Round 1
// baseline (130.477 us; speedup 1.0000x reference)
//
#include <hip/hip_runtime.h>

// GausLJLayer: per-element LJ (3 terms) + Gaussian (4 terms) energy/force.
// Memory-bound: 88 B in + 8 B out per element. LDS-stage the (B,21) param
// rows so HBM reads are fully coalesced.

constexpr int BLOCK = 256;
constexpr int NPAR  = 21;   // 3*3 LJ + 4*3 Gauss

__global__ __launch_bounds__(BLOCK)
void gauslj_kernel(const float* __restrict__ distance,
                   const float* __restrict__ param,
                   float* __restrict__ out,   // [0..n) energies, [n..2n) forces
                   int n)
{
    __shared__ float sp[BLOCK * NPAR];   // 21504 B

    const int t    = threadIdx.x;
    const long long base = (long long)blockIdx.x * BLOCK;
    const long long gbase = base * NPAR;
    const long long ptotal = (long long)n * NPAR;

    // Coalesced staging: the block's param rows are one contiguous range of
    // BLOCK*NPAR floats. 21 loads/thread, lane-contiguous.
    #pragma unroll
    for (int j = 0; j < NPAR; ++j) {
        long long g = gbase + j * BLOCK + t;
        if (g < ptotal) sp[j * BLOCK + t] = param[g];
    }
    __syncthreads();

    const long long i = base + t;
    if (i >= n) return;

    const float d     = distance[i];
    const float inv_d = 1.0f / d;
    const float id2   = inv_d * inv_d;
    const float id4   = id2 * id2;
    const float id6   = id4 * id2;
    const float id7   = id6 * inv_d;
    const float id12  = id6 * id6;
    const float id13  = id12 * inv_d;

    const float* p = &sp[t * NPAR];   // stride-21 rows: conflict-free (gcd(21,32)=1)

    float e = 0.0f, f = 0.0f;

    // LJ terms: p[3k+1]=c, p[3k+2]=sigma  (p[3k+0] unused, matches reference)
    #pragma unroll
    for (int k = 0; k < 3; ++k) {
        const float c  = p[3 * k + 1];
        const float s  = p[3 * k + 2];
        const float s2 = s * s;
        const float s6 = s2 * s2 * s2;
        const float s12 = s6 * s6;
        const float ir6  = s6 * id6;    // (sigma/d)^6
        const float ir12 = s12 * id12;
        e += 4.0f * c * (ir12 - ir6);
        f += -4.0f * c * (4.0f * s6 * id7 - 12.0f * s12 * id13);
    }

    // Gaussian terms: p[9+3k]=amplitude, p[9+3k+1]=mean, p[9+3k+2]=stddev
    #pragma unroll
    for (int k = 0; k < 4; ++k) {
        const float a   = p[9 + 3 * k + 0];
        const float mu  = p[9 + 3 * k + 1];
        const float sd  = p[9 + 3 * k + 2];
        const float dm  = d - mu;
        const float inv_sd2 = 1.0f / (sd * sd);
        const float ex  = expf(-0.5f * dm * dm * inv_sd2);
        e += a * ex;
        // -(a*dm*ex*dm^2/sd^2)/sd^2
        f += -(a * dm * ex) * (dm * dm) * inv_sd2 * inv_sd2;
    }

    out[i]     = e;
    out[n + i] = f;
}

extern "C" void kernel_launch(void* const* d_in, const int* in_sizes, int n_in,
                              void* d_out, int out_size, void* d_ws, size_t ws_size,
                              hipStream_t stream) {
    const float* distance = (const float*)d_in[0];
    const float* param    = (const float*)d_in[1];
    float* out            = (float*)d_out;
    const int n = in_sizes[0];

    const int grid = (n + BLOCK - 1) / BLOCK;
    gauslj_kernel<<<grid, BLOCK, 0, stream>>>(distance, param, out, n);
}

// Round 2
// 76.761 us; speedup vs baseline: 1.6998x; 1.6998x over previous
//
#include <hip/hip_runtime.h>

// GausLJLayer: per-element LJ (3 terms) + Gaussian (4 terms) energy/force.
// Memory-bound: 88 B in + 8 B out per element (403 MB total). Params staged
// to LDS via global_load_lds (16B width) for fully-coalesced reads.

constexpr int BLOCK = 256;
constexpr int NPAR  = 21;                      // 3*3 LJ + 4*3 Gauss
constexpr int NV4   = BLOCK * NPAR / 4;        // 1344 float4 per block

__global__ __launch_bounds__(BLOCK)
void gauslj_kernel(const float* __restrict__ distance,
                   const float* __restrict__ param,
                   float* __restrict__ out,    // [0..n) energies, [n..2n) forces
                   int n)
{
    __shared__ float4 sp4[NV4];                // 21504 B, 16B-aligned
    float* sp = (float*)sp4;

    const int t = threadIdx.x;
    const long long base = (long long)blockIdx.x * BLOCK;

    if (base + BLOCK <= n) {
        // ---- fast path: unguarded, direct global->LDS staging ----
        // Block's param rows are one contiguous, 16B-aligned range of
        // NV4 float4s (base*NPAR*4 bytes, divisible by 16).
        const float4* g4 = (const float4*)(param + base * NPAR);
        const int wbase = t & ~63;             // wave-uniform LDS base index
        #pragma unroll
        for (int j = 0; j < 6; ++j) {
            const int idx = j * 256 + t;
            if (idx < NV4) {                   // wave-uniform predicate
                __builtin_amdgcn_global_load_lds(
                    (const __attribute__((address_space(1))) void*)(g4 + idx),
                    (__attribute__((address_space(3))) void*)(sp4 + j * 256 + wbase),
                    16, 0, 0);
            }
        }
    } else {
        // ---- tail path: guarded scalar staging (last block only) ----
        const long long gbase  = base * NPAR;
        const long long ptotal = (long long)n * NPAR;
        for (int j = 0; j < NPAR; ++j) {
            long long g = gbase + j * BLOCK + t;
            if (g < ptotal) sp[j * BLOCK + t] = param[g];
        }
    }
    __syncthreads();

    const long long i = base + t;
    if (i >= n) return;

    const float d     = distance[i];
    const float inv_d = __builtin_amdgcn_rcpf(d);
    const float id2   = inv_d * inv_d;
    const float id4   = id2 * id2;
    const float id6   = id4 * id2;
    const float id7   = id6 * inv_d;
    const float id12  = id6 * id6;
    const float id13  = id12 * inv_d;

    const float* p = &sp[t * NPAR];   // stride-21 rows: gcd(21,32)=1, conflict-free

    float e = 0.0f, f = 0.0f;

    // LJ terms: p[3k+1]=c, p[3k+2]=sigma  (p[3k+0] unused, matches reference)
    #pragma unroll
    for (int k = 0; k < 3; ++k) {
        const float c   = p[3 * k + 1];
        const float s   = p[3 * k + 2];
        const float s2  = s * s;
        const float s6  = s2 * s2 * s2;
        const float s12 = s6 * s6;
        e += 4.0f * c * (s12 * id12 - s6 * id6);
        f += -4.0f * c * (4.0f * s6 * id7 - 12.0f * s12 * id13);
    }

    // Gaussian terms: p[9+3k]=amplitude, p[9+3k+1]=mean, p[9+3k+2]=stddev
    #pragma unroll
    for (int k = 0; k < 4; ++k) {
        const float a       = p[9 + 3 * k + 0];
        const float mu      = p[9 + 3 * k + 1];
        const float sd      = p[9 + 3 * k + 2];
        const float dm      = d - mu;
        const float inv_sd2 = __builtin_amdgcn_rcpf(sd * sd);
        const float ex      = __expf(-0.5f * dm * dm * inv_sd2);
        e += a * ex;
        f += -(a * dm * ex) * (dm * dm) * inv_sd2 * inv_sd2;
    }

    __builtin_nontemporal_store(e, &out[i]);
    __builtin_nontemporal_store(f, &out[n + i]);
}

extern "C" void kernel_launch(void* const* d_in, const int* in_sizes, int n_in,
                              void* d_out, int out_size, void* d_ws, size_t ws_size,
                              hipStream_t stream) {
    const float* distance = (const float*)d_in[0];
    const float* param    = (const float*)d_in[1];
    float* out            = (float*)d_out;
    const int n = in_sizes[0];

    const int grid = (n + BLOCK - 1) / BLOCK;
    gauslj_kernel<<<grid, BLOCK, 0, stream>>>(distance, param, out, n);
}